// Round 10
// baseline (269.642 us; speedup 1.0000x reference)
//
#include <hip/hip_runtime.h>
#include <hip/hip_bf16.h>
#include <hip/hip_fp16.h>
#include <hip/hip_fp8.h>

// GCN: N=100000 nodes, E=1600000 edges, B=64 graphs, 20 -> 128 -> 128 -> 256.
// Strategy log:
//  - gcn_conv(h,W) = (scatter_norm(h)) @ W; mean-pool commutes with W3.
//  - R1 sorted-batch seg starts; R3 two-level bucket-sort CSR.
//  - R4-R8: gathers pinned by random line traffic; fp8 payloads (R7).
//  - R9 lesson: edge-parallel scatter or bust. R11/14: GEMMs on MFMA.
//  - R12/13: layer-3 -> dense per-bucket GEMM + partial slabs + reduce.
//  - R15: layer2 gather: one row per 16-lane group -> 81 -> 48us (floor).
//  - R16: pool3m raw-fp8 staging; bf16 slabs; gather20b fused into conv1.
//  - R17/18: packed fp8 decode + v_cvt_pk_bf16_f32; k_prep merge. 304->295.
//  - R19 FAILED: NT stores broke CROSS-KERNEL L2 reuse.
//  - R20: k_scatter 256x1024: 295->292.6.
//  - R21: pool_reduce uint4+shfl: WIN (-16). Gather unroll 8: REGRESSION.
//    Lesson: random-gather kernels live on TLP, not ILP.
//  - R22: unrolls back to 4; 273.9. layer2 at random-line floor (47us).
//  - R23: SB=64: traffic fix must not sacrifice CU coverage (54us, reverted).
//  - R24: 256 blk + XCD row perm l=(b&7)*32+(b>>3): 273.9->260.3.
//  - R25: scatter LDS staging sort: only -1.6 (260.3->258.7) — scatter was
//    already near floor post-R24. Gather floors PROVEN compulsory: per XCD
//    86% of h8a lines touched -> 8x11MB=88MB L2-miss fill; any split scheme
//    costs >= 8 x table = 102MB. Stop touching gathers/scatter.
//  - R26 (this round): pool output path. bf16 partial slabs (12.8MB) +
//    k_pool_reduce  ->  8 XCD-local fp32 atomic slabs (32KB each, idx
//    blockIdx&7; each address gets ~98 well-spread adds, different dwords
//    of a line are independent at L2 -> no hot-spot). pool_reduce DELETED;
//    k_final sums 8 slabs inline; slabs zeroed by 64 extra k_prep blocks.
//    TLP preserved (782 pool3m blocks). fp32 slabs = MORE accurate than
//    bf16 partials. Predict -4..8us, total ~251-255; else declare floor.

typedef unsigned short ushort_t;
typedef unsigned int uint_t;
typedef __attribute__((ext_vector_type(8))) short bf16x8;
typedef __attribute__((ext_vector_type(4))) float f32x4;
typedef __attribute__((ext_vector_type(2))) float f32x2;

constexpr int N  = 100000;
constexpr int E  = 1600000;
constexpr int B  = 64;
constexpr int IND = 20;
constexpr int HID = 128;
constexpr int OUTD = 256;

constexpr int NBUK = (N + 127) / 128;   // 782 buckets of 128 nodes
constexpr int GB   = 256;               // hist rows / scatter blocks
constexpr int EPB  = E / GB;            // 6250 edges per hist row
constexpr int BMAX = 3072;              // LDS cap per bucket (mean 2048, sd ~45)
constexpr int NSEG = (N + 255) / 256;   // seg-start blocks in k_prep
constexpr int NSLAB = 8;                // XCD-local fp32 pool slabs

// bf16 helpers (RNE pack, shift-unpack)
__device__ inline ushort_t f2bf(float f) {
  union { float f; uint_t u; } v; v.f = f;
  uint_t r = v.u + 0x7fffu + ((v.u >> 16) & 1u);
  return (ushort_t)(r >> 16);
}
__device__ inline float bflo(uint_t u) { return __uint_as_float(u << 16); }
__device__ inline float bfhi(uint_t u) { return __uint_as_float(u & 0xffff0000u); }

// packed f32x2 -> bf16x2 (RNE, identical to f2bf pair) in ONE VALU op
__device__ inline uint_t pkbf(float a, float b) {
  uint_t r;
  asm("v_cvt_pk_bf16_f32 %0, %1, %2" : "=v"(r) : "v"(a), "v"(b));
  return r;
}

// fp8 e4m3 helpers (HW cvt on gfx950; hip_fp8.h fallback)
#if defined(__has_builtin)
#if __has_builtin(__builtin_amdgcn_cvt_f32_fp8) && __has_builtin(__builtin_amdgcn_cvt_pk_fp8_f32)
#define FP8_HW 1
#endif
#if __has_builtin(__builtin_amdgcn_cvt_pk_f32_fp8)
#define FP8_PK 1
#endif
#endif

template <int S>
__device__ inline float fp8dec(uint_t u) {
#ifdef FP8_HW
  return __builtin_amdgcn_cvt_f32_fp8(u, S);
#else
  __hip_fp8_storage_t b = (__hip_fp8_storage_t)((u >> (8 * S)) & 0xffu);
  __half_raw hr = __hip_cvt_fp8_to_halfraw(b, __HIP_E4M3);
  return __half2float(*(__half*)&hr);
#endif
}

// packed decode: word W of u (bytes 2W,2W+1) -> float2 in one inst
template <int W>
__device__ inline f32x2 fp8dec2(uint_t u) {
#ifdef FP8_PK
  return __builtin_amdgcn_cvt_pk_f32_fp8(u, W != 0);
#else
  f32x2 r; r.x = fp8dec<W * 2>(u); r.y = fp8dec<W * 2 + 1>(u); return r;
#endif
}

template <bool W>
__device__ inline uint_t fp8pk2(float a, float b, uint_t old) {
#ifdef FP8_HW
  return __builtin_amdgcn_cvt_pk_fp8_f32(a, b, old, W);
#else
  uint_t lo = (uint_t)__hip_cvt_float_to_fp8(a, __HIP_SATFINITE, __HIP_E4M3);
  uint_t hi = (uint_t)__hip_cvt_float_to_fp8(b, __HIP_SATFINITE, __HIP_E4M3);
  uint_t pair = lo | (hi << 8);
  return W ? ((old & 0x0000ffffu) | (pair << 16)) : ((old & 0xffff0000u) | pair);
#endif
}

// two fp8 bytes (from different LDS rows) -> packed bf16 pair (b0 low)
__device__ inline uint_t fp8pair2bf(uint_t b0, uint_t b1) {
#ifdef FP8_PK
  f32x2 f = fp8dec2<0>(b0 | (b1 << 8));
  return pkbf(f.x, f.y);
#else
  return (uint_t)f2bf(fp8dec<0>(b0)) | ((uint_t)f2bf(fp8dec<0>(b1)) << 16);
#endif
}

// ---------------- merged prep: hist + weight packs + seg starts + slab zero --------
// blocks [0,GB): edge histograms; [GB,GB+96): weight packs;
// [GB+96, GB+96+NSEG): seg starts; last 64: zero pool slabs.

__global__ __launch_bounds__(256) void k_prep(const int* __restrict__ eidx,
                                              int* __restrict__ histd,
                                              int* __restrict__ hists,
                                              const float* __restrict__ W2,
                                              const float* __restrict__ W1,
                                              const float* __restrict__ resW,
                                              ushort_t* __restrict__ wpack,
                                              ushort_t* __restrict__ w1pack,
                                              const int* __restrict__ batch,
                                              int* __restrict__ starts,
                                              float* __restrict__ slabs) {
  const int bid = blockIdx.x;
  if (bid < GB) {
    __shared__ int hd[NBUK], hs[NBUK];
    for (int i = threadIdx.x; i < NBUK; i += 256) { hd[i] = 0; hs[i] = 0; }
    __syncthreads();
    const long base = (long)bid * EPB;
    for (int i = threadIdx.x; i < EPB; i += 256) {
      atomicAdd(&hs[eidx[base + i] >> 7], 1);
      atomicAdd(&hd[eidx[E + base + i] >> 7], 1);
    }
    __syncthreads();
    for (int i = threadIdx.x; i < NBUK; i += 256) {
      histd[(long)bid * NBUK + i] = hd[i];
      hists[(long)bid * NBUK + i] = hs[i];
    }
  } else if (bid < GB + 96) {
    // Pack W2 into MFMA B-frag order (16384) AND [W1|resW] K=64 pack (8192).
    int idx = (bid - GB) * 256 + threadIdx.x;
    if (idx < 16384) {
      int j = idx & 7, L = (idx >> 3) & 63, kt = (idx >> 9) & 3, t = idx >> 11;
      int k = kt * 32 + ((L >> 4) & 3) * 8 + j;
      int n = t * 16 + (L & 15);
      wpack[idx] = f2bf(W2[k * HID + n]);
    } else {
      int i2 = idx - 16384;
      int j = i2 & 7, L = (i2 >> 3) & 63, kt = (i2 >> 9) & 1, t = i2 >> 10;
      int k = kt * 32 + ((L >> 4) & 3) * 8 + j;
      int n = t * 16 + (L & 15);
      float v = 0.f;
      if (k < IND) v = W1[k * HID + n];
      else if (k >= 32 && k < 32 + IND) v = resW[(k - 32) * HID + n];
      w1pack[i2] = f2bf(v);
    }
  } else if (bid < GB + 96 + NSEG) {
    int i = (bid - GB - 96) * 256 + threadIdx.x;
    if (i >= N) return;
    int b = batch[i];
    int prev = (i == 0) ? -1 : batch[i - 1];
    for (int g = prev + 1; g <= b; ++g) starts[g] = i;  // fires only at boundaries
    if (i == N - 1)
      for (int g = b + 1; g <= B; ++g) starts[g] = N;
  } else {
    // zero the NSLAB x B x HID fp32 pool slabs (64 blocks x 1024 floats)
    int z = (bid - (GB + 96 + NSEG)) * 1024 + threadIdx.x * 4;
    *(float4*)&slabs[z] = make_float4(0.f, 0.f, 0.f, 0.f);
  }
}

// ---------------- CSR builds: bucket sorts by dst AND by src ----------------

// Both per-bucket scans in one launch: grid = 2*NBUK.
__global__ __launch_bounds__(256) void k_bscan2x(int* __restrict__ histd,
                                                 int* __restrict__ btd,
                                                 int* __restrict__ hists,
                                                 int* __restrict__ bts) {
  __shared__ int s[256];
  const int which = (blockIdx.x >= NBUK);
  const int j = which ? blockIdx.x - NBUK : blockIdx.x;
  int* hist = which ? hists : histd;
  int* btotal = which ? bts : btd;
  const int tid = threadIdx.x;
  int v = hist[(long)tid * NBUK + j];
  s[tid] = v;
  for (int off = 1; off < 256; off <<= 1) {
    __syncthreads();
    int x = (tid >= off) ? s[tid - off] : 0;
    __syncthreads();
    s[tid] += x;
  }
  hist[(long)tid * NBUK + j] = s[tid] - v;   // exclusive within bucket
  if (tid == 255) btotal[j] = s[255];
}

// Both bucket-total scans in one launch: grid = 2.
__global__ __launch_bounds__(256) void k_bktscan2x(const int* __restrict__ btd,
                                                   int* __restrict__ bexcl,
                                                   const int* __restrict__ bts,
                                                   int* __restrict__ bexcl2,
                                                   int* __restrict__ rowptr) {
  __shared__ int s[256];
  const int* bt = blockIdx.x ? bts : btd;
  int* bx = blockIdx.x ? bexcl2 : bexcl;
  int tid = threadIdx.x;
  int base = tid * 4;
  int v0 = (base + 0 < NBUK) ? bt[base + 0] : 0;
  int v1 = (base + 1 < NBUK) ? bt[base + 1] : 0;
  int v2 = (base + 2 < NBUK) ? bt[base + 2] : 0;
  int v3 = (base + 3 < NBUK) ? bt[base + 3] : 0;
  int p0 = v0, p1 = p0 + v1, p2 = p1 + v2, p3 = p2 + v3;
  s[tid] = p3;
  for (int off = 1; off < 256; off <<= 1) {
    __syncthreads();
    int x = (tid >= off) ? s[tid - off] : 0;
    __syncthreads();
    s[tid] += x;
  }
  int excl = s[tid] - p3;
  if (base + 0 < NBUK) bx[base + 1] = excl + p0;
  if (base + 1 < NBUK) bx[base + 2] = excl + p1;
  if (base + 2 < NBUK) bx[base + 3] = excl + p2;
  if (base + 3 < NBUK) bx[base + 4] = excl + p3;
  if (tid == 0) { bx[0] = 0; if (blockIdx.x == 0) rowptr[N] = E; }
}

// Merged scatter with LDS staging sort (R25).
// ebuf (dst-order):  src(20b) | dstlow(7b)<<20
// ebuf2 (src-order): srclow(7b)<<17 | dst(17b)
// Per ordering: local count -> block scan -> bucket-ordered staged[] ->
// copy-out in staged order (coalesced write runs). R24 XCD row perm kept.
__global__ __launch_bounds__(1024) void k_scatter(const int* __restrict__ eidx,
                                                  const int* __restrict__ histd,
                                                  const int* __restrict__ bexcl,
                                                  const int* __restrict__ hists,
                                                  const int* __restrict__ bexcl2,
                                                  int* __restrict__ ebuf,
                                                  int* __restrict__ ebuf2) {
  __shared__ int lhist[NBUK];      // counts, then cursors
  __shared__ int lscan[NBUK];      // exclusive scan (staged base per bucket)
  __shared__ int gbase[NBUK];      // global base per bucket
  __shared__ int stmp[1024];       // scan temp
  __shared__ int staged[EPB];      // bucket-ordered payloads (25 KB)
  __shared__ ushort_t sbuk[EPB];   // bucket of each staged slot (12.5 KB)
  const int tid = threadIdx.x;
  const int l = ((blockIdx.x & 7) << 5) + (blockIdx.x >> 3);   // bijective 0..255
  const long hrow = (long)l * NBUK;
  const long base = (long)l * EPB;

#pragma unroll
  for (int pass = 0; pass < 2; ++pass) {
    const int* hist = pass ? hists : histd;
    const int* bx = pass ? bexcl2 : bexcl;
    int* out = pass ? ebuf2 : ebuf;
    // init: zero counts, load global bases
    for (int i = tid; i < NBUK; i += 1024) {
      lhist[i] = 0;
      gbase[i] = bx[i] + hist[hrow + i];
    }
    __syncthreads();
    // count
    for (int i = tid; i < EPB; i += 1024) {
      int key = eidx[(pass ? 0 : E) + base + i];   // dst for pass0, src for pass1
      atomicAdd(&lhist[key >> 7], 1);
    }
    __syncthreads();
    // block scan (Hillis-Steele over 1024, NBUK=782 zero-padded)
    {
      int v = (tid < NBUK) ? lhist[tid] : 0;
      stmp[tid] = v;
      for (int off = 1; off < 1024; off <<= 1) {
        __syncthreads();
        int x2 = (tid >= off) ? stmp[tid - off] : 0;
        __syncthreads();
        stmp[tid] += x2;
      }
      __syncthreads();
      if (tid < NBUK) {
        int ex = stmp[tid] - v;
        lscan[tid] = ex;
        lhist[tid] = ex;   // cursor
      }
    }
    __syncthreads();
    // scatter into staged (bucket-ordered)
    for (int i = tid; i < EPB; i += 1024) {
      int s = eidx[base + i];
      int d = eidx[E + base + i];
      int b = (pass ? s : d) >> 7;
      int pos = atomicAdd(&lhist[b], 1);
      staged[pos] = pass ? (((s & 127) << 17) | d) : (s | ((d & 127) << 20));
      sbuk[pos] = (ushort_t)b;
    }
    __syncthreads();
    // coalesced copy-out: staged order == global order within each bucket run
    for (int i = tid; i < EPB; i += 1024) {
      int b = sbuk[i];
      out[gbase[b] + (i - lscan[b])] = staged[i];
    }
    __syncthreads();
  }
}

// One block per dst-bucket: LDS counting sort -> rowptr/dinv/colsrc + xs16.
__global__ __launch_bounds__(256) void k_csr(const int* __restrict__ ebuf,
                                             const int* __restrict__ bexcl,
                                             const float* __restrict__ x,
                                             int* __restrict__ rowptr,
                                             float* __restrict__ dinv,
                                             int* __restrict__ colsrc,
                                             ushort_t* __restrict__ xs16) {
  __shared__ int deg[128], s[128], cur[128];
  __shared__ float dv[128];
  __shared__ int lout[BMAX];
  const int j = blockIdx.x, tid = threadIdx.x;
  const int e0 = bexcl[j], e1 = bexcl[j + 1];
  const int cnt = e1 - e0;
  if (tid < 128) deg[tid] = 0;
  __syncthreads();
  for (int i = tid; i < cnt; i += 256)
    atomicAdd(&deg[(ebuf[e0 + i] >> 20) & 127], 1);
  __syncthreads();
  int v = (tid < 128) ? deg[tid] : 0;
  if (tid < 128) s[tid] = v;
  for (int off = 1; off < 128; off <<= 1) {
    __syncthreads();
    int x2 = (tid < 128 && tid >= off) ? s[tid - off] : 0;
    __syncthreads();
    if (tid < 128) s[tid] += x2;
  }
  __syncthreads();
  if (tid < 128) {
    int ex = s[tid] - v;
    cur[tid] = ex;
    float d = rsqrtf((float)(1 + v));   // deg includes self-loop
    dv[tid] = d;
    int node = j * 128 + tid;
    if (node < N) {
      rowptr[node] = e0 + ex;
      dinv[node] = d;
    }
  }
  __syncthreads();
  if (cnt <= BMAX) {
    for (int i = tid; i < cnt; i += 256) {
      int p = ebuf[e0 + i];
      int pos = atomicAdd(&cur[(p >> 20) & 127], 1);
      lout[pos] = p & 0xFFFFF;
    }
    __syncthreads();
    for (int i = tid; i < cnt; i += 256) colsrc[e0 + i] = lout[i];
  } else {  // safety fallback
    for (int i = tid; i < cnt; i += 256) {
      int p = ebuf[e0 + i];
      int pos = atomicAdd(&cur[(p >> 20) & 127], 1);
      colsrc[e0 + pos] = p & 0xFFFFF;
    }
  }
  for (int idx = tid; idx < 128 * IND; idx += 256) {
    int n = idx / IND;
    long node = (long)j * 128 + n;
    if (node < N)
      xs16[node * IND + idx % IND] = f2bf(x[node * IND + idx % IND] * dv[n]);
  }
}

// ---------------- layer 1: fused 20-dim gather + MFMA conv1 + LN + ReLU ----------------

// A-tile: 16 nodes x K=64 (k<20: gathered aggx, 32<=k<52: bf16(x), else 0).
constexpr int ASTR = 72;    // bf16 A stride
constexpr int CSTR = 132;   // fp32 C stride

__global__ __launch_bounds__(256) void k_layer1(const ushort_t* __restrict__ xs16,
                                                const float* __restrict__ x,
                                                const int* __restrict__ rowptr,
                                                const int* __restrict__ colsrc,
                                                const ushort_t* __restrict__ w1pack,
                                                const float* __restrict__ b1,
                                                const float* __restrict__ resb,
                                                const float* __restrict__ g1,
                                                const float* __restrict__ bb1,
                                                const float* __restrict__ dinv,
                                                unsigned char* __restrict__ h8a) {
  __shared__ ushort_t A[16 * ASTR];   // 2.25 KB
  __shared__ float Cs[16 * CSTR];     // 8.25 KB
  const int tid = threadIdx.x;
  const long node0 = (long)blockIdx.x * 16;           // grid = N/16 exact
  // zero A, stage x into k in [32,52)
  for (int idx = tid; idx < 16 * ASTR; idx += 256) A[idx] = 0;
  __syncthreads();
  for (int idx = tid; idx < 16 * IND; idx += 256) {
    int n = idx / IND, k = idx % IND;
    A[n * ASTR + 32 + k] = f2bf(x[(node0 + n) * IND + k]);
  }
  // gather phase: 10 threads/node x 16 nodes = 160 active threads,
  // each owns 2 channels, serial over edges (unroll 4; 8 raised VGPR/cut occ).
  if (tid < 160) {
    int n = tid / 10, cc = (tid % 10) * 2;
    long i = node0 + n;
    float di = dinv[i];
    uint_t u = *(const uint_t*)(xs16 + i * IND + cc);
    float a0 = bflo(u), a1 = bfhi(u);
    int e0 = rowptr[i], e1 = rowptr[i + 1];
#pragma unroll 4
    for (int e = e0; e < e1; ++e) {
      int s = colsrc[e];
      uint_t v = *(const uint_t*)(xs16 + (long)s * IND + cc);
      a0 += bflo(v); a1 += bfhi(v);
    }
    *(uint_t*)&A[n * ASTR + cc] = pkbf(a0 * di, a1 * di);
  }
  __syncthreads();
  const int lane = tid & 63, w = tid >> 6;
  {
    const int arow = lane & 15, aq = lane >> 4;
    f32x4 acc0 = {0.f, 0.f, 0.f, 0.f}, acc1 = {0.f, 0.f, 0.f, 0.f};
    const int t0 = w * 2, t1 = t0 + 1;
#pragma unroll
    for (int kt = 0; kt < 2; ++kt) {
      bf16x8 af = *(const bf16x8*)&A[arow * ASTR + kt * 32 + aq * 8];
      bf16x8 b0 = *(const bf16x8*)&w1pack[(t0 * 2 + kt) * 512 + lane * 8];
      bf16x8 b1f = *(const bf16x8*)&w1pack[(t1 * 2 + kt) * 512 + lane * 8];
      acc0 = __builtin_amdgcn_mfma_f32_16x16x32_bf16(af, b0, acc0, 0, 0, 0);
      acc1 = __builtin_amdgcn_mfma_f32_16x16x32_bf16(af, b1f, acc1, 0, 0, 0);
    }
#pragma unroll
    for (int r = 0; r < 4; ++r) {
      Cs[(aq * 4 + r) * CSTR + t0 * 16 + arow] = acc0[r];
      Cs[(aq * 4 + r) * CSTR + t1 * 16 + arow] = acc1[r];
    }
  }
  __syncthreads();
  const int nidx = tid >> 5, col = (tid & 31) * 4;
  float4 bz = *(const float4*)&b1[col];
  float4 rz = *(const float4*)&resb[col];
  bz.x += rz.x; bz.y += rz.y; bz.z += rz.z; bz.w += rz.w;
  float4 gz = *(const float4*)&g1[col];
  float4 bbz = *(const float4*)&bb1[col];
#pragma unroll
  for (int m = 0; m < 2; ++m) {
    int nl = nidx + m * 8;
    long nm = node0 + nl;
    float4 o = *(const float4*)&Cs[nl * CSTR + col];
    o.x += bz.x; o.y += bz.y; o.z += bz.z; o.w += bz.w;
    float s = o.x + o.y + o.z + o.w;
    float q = o.x * o.x + o.y * o.y + o.z * o.z + o.w * o.w;
#pragma unroll
    for (int off = 1; off <= 16; off <<= 1) {
      s += __shfl_xor(s, off);
      q += __shfl_xor(q, off);
    }
    float mu = s * (1.f / 128.f);
    float var = q * (1.f / 128.f) - mu * mu;
    float rs = rsqrtf(var + 1e-5f);
    float y0 = fmaxf(fmaf((o.x - mu) * rs, gz.x, bbz.x), 0.f);
    float y1 = fmaxf(fmaf((o.y - mu) * rs, gz.y, bbz.y), 0.f);
    float y2 = fmaxf(fmaf((o.z - mu) * rs, gz.z, bbz.z), 0.f);
    float y3 = fmaxf(fmaf((o.w - mu) * rs, gz.w, bbz.w), 0.f);
    float di = dinv[nm];
    uint_t p = fp8pk2<false>(y0 * di, y1 * di, 0u);
    p = fp8pk2<true>(y2 * di, y3 * di, p);
    *(uint_t*)&h8a[nm * HID + col] = p;
  }
}

// ---------------- layer 2: fp8 gather + MFMA GEMM + LN + ReLU ----------------

constexpr int XSTR = 136;   // bf16 stride

__global__ __launch_bounds__(256) void k_layer2(const unsigned char* __restrict__ h8a,
                                                const float* __restrict__ dinv,
                                                const int* __restrict__ rowptr,
                                                const int* __restrict__ colsrc,
                                                const ushort_t* __restrict__ wpack,
                                                const float* __restrict__ bias,
                                                const float* __restrict__ g2,
                                                const float* __restrict__ bb2,
                                                unsigned char* __restrict__ h8b) {
  __shared__ ushort_t XsB[16 * XSTR];   // 4.25 KB bf16 gathered X
  __shared__ float Cs[16 * CSTR];       // 8.25 KB fp32 GEMM out
  const int tid = threadIdx.x;
  const long node0 = (long)blockIdx.x * 16;           // grid = N/16 exact
  const int lane = tid & 63, w = tid >> 6;
  // ---- phase 1: one ROW per 16-lane group; rows parallel; no reduce ----
  // packed decode: 4x v_cvt_pk_f32_fp8 + 4x f32x2 add per edge
  // (unroll 4: TLP > ILP for random gathers; unroll 8 cost 10% occupancy)
  {
    const int grp = lane >> 4, l16 = lane & 15, c8 = l16 * 8;
    const long i = node0 + w * 4 + grp;
    const float di = dinv[i];
    f32x2 a0, a1, a2, a3;
    {   // self term (row already carries dinv[i])
      uint2 u = *(const uint2*)(h8a + i * HID + c8);
      a0 = fp8dec2<0>(u.x); a1 = fp8dec2<1>(u.x);
      a2 = fp8dec2<0>(u.y); a3 = fp8dec2<1>(u.y);
    }
    const int e0 = rowptr[i], e1 = rowptr[i + 1];
#pragma unroll 4
    for (int e = e0; e < e1; ++e) {
      int s = colsrc[e];
      uint2 u = *(const uint2*)(h8a + (long)s * HID + c8);
      a0 += fp8dec2<0>(u.x); a1 += fp8dec2<1>(u.x);
      a2 += fp8dec2<0>(u.y); a3 += fp8dec2<1>(u.y);
    }
    uint_t p0 = pkbf(a0.x * di, a0.y * di);
    uint_t p1 = pkbf(a1.x * di, a1.y * di);
    uint_t p2 = pkbf(a2.x * di, a2.y * di);
    uint_t p3 = pkbf(a3.x * di, a3.y * di);
    *(uint4*)&XsB[(w * 4 + grp) * XSTR + c8] = make_uint4(p0, p1, p2, p3);
  }
  __syncthreads();
  // ---- phase 2: MFMA. Wave w covers n-tiles {2w, 2w+1}. ----
  {
    const int arow = lane & 15, aq = lane >> 4;
    f32x4 acc0 = {0.f, 0.f, 0.f, 0.f}, acc1 = {0.f, 0.f, 0.f, 0.f};
    const int t0 = w * 2, t1 = w * 2 + 1;
#pragma unroll
    for (int kt = 0; kt < 4; ++kt) {
      bf16x8 af = *(const bf16x8*)&XsB[arow * XSTR + kt * 32 + aq * 8];
      bf16x8 b0 = *(const bf16x8*)&wpack[(t0 * 4 + kt) * 512 + lane * 8];
      bf16x8 b1 = *(const bf16x8*)&wpack[(t1 * 4 + kt) * 512 + lane * 8];
      acc0 = __builtin_amdgcn_mfma_f32_16x16x32_bf16(af, b0, acc0, 0, 0, 0);
      acc1 = __builtin_amdgcn_mfma_f32_16x16x32_bf16(af, b1, acc1, 0, 0, 0);
    }
#pragma unroll
    for (int r = 0; r < 4; ++r) {
      Cs[(aq * 4 + r) * CSTR + t0 * 16 + arow] = acc0[r];
      Cs[(aq * 4 + r) * CSTR + t1 * 16 + arow] = acc1[r];
    }
  }
  __syncthreads();
  // ---- phase 3: bias + residual(fp8 h8a) + LN + ReLU + fp8 store ----
  const int nidx = tid >> 5;
  const int col = (tid & 31) * 4;
  float4 bz = *(const float4*)&bias[col];
  float4 gz = *(const float4*)&g2[col];
  float4 bbz = *(const float4*)&bb2[col];
#pragma unroll
  for (int m = 0; m < 2; ++m) {
    int nl = nidx + m * 8;
    long nm = node0 + nl;
    float di = dinv[nm];
    float rdi = 1.0f / di;
    uint_t ur = *(const uint_t*)&h8a[nm * HID + col];   // fp8 residual (L2-hot)
    f32x2 r01 = fp8dec2<0>(ur), r23 = fp8dec2<1>(ur);
    float4 o = *(const float4*)&Cs[nl * CSTR + col];
    o.x += bz.x + r01.x * rdi;
    o.y += bz.y + r01.y * rdi;
    o.z += bz.z + r23.x * rdi;
    o.w += bz.w + r23.y * rdi;
    float s = o.x + o.y + o.z + o.w;
    float q = o.x * o.x + o.y * o.y + o.z * o.z + o.w * o.w;
#pragma unroll
    for (int off = 1; off <= 16; off <<= 1) {
      s += __shfl_xor(s, off);
      q += __shfl_xor(q, off);
    }
    float mu = s * (1.f / 128.f);
    float var = q * (1.f / 128.f) - mu * mu;
    float rs = rsqrtf(var + 1e-5f);
    float y0 = fmaxf(fmaf((o.x - mu) * rs, gz.x, bbz.x), 0.f);
    float y1 = fmaxf(fmaf((o.y - mu) * rs, gz.y, bbz.y), 0.f);
    float y2 = fmaxf(fmaf((o.z - mu) * rs, gz.z, bbz.z), 0.f);
    float y3 = fmaxf(fmaf((o.w - mu) * rs, gz.w, bbz.w), 0.f);
    uint_t p = fp8pk2<false>(y0 * di, y1 * di, 0u);
    p = fp8pk2<true>(y2 * di, y3 * di, p);
    *(uint_t*)&h8b[nm * HID + col] = p;
  }
}

// ---------------- layer 3: per-bucket dense pool GEMM ----------------

constexpr int RSTR8 = 136;  // fp8 row stride (bytes, 8B aligned)
constexpr int CP    = 132;  // fp32 row stride for C

__global__ __launch_bounds__(256) void k_pool3m(const unsigned char* __restrict__ h8b,
                                                const int* __restrict__ bexcl2,
                                                const int* __restrict__ ebuf2,
                                                const int* __restrict__ batch,
                                                const float* __restrict__ dinv,
                                                float* __restrict__ slabs) {
  __shared__ float Cm[B * CP];            // 33.8 KB
  __shared__ unsigned char R8[128 * RSTR8];  // 17.4 KB raw fp8 rows
  const int j = blockIdx.x, tid = threadIdx.x;
  const long nbase = (long)j * 128;
  const int validRows = min(128, N - (int)nbase);
  for (int i = tid; i < B * CP; i += 256) Cm[i] = 0.f;
  for (int i = tid; i < 128 * (HID / 16); i += 256) {   // 16B per thread
    int s = i >> 3;
    int ch = (i & 7) * 16;
    uint4 pk = make_uint4(0u, 0u, 0u, 0u);
    if (s < validRows)
      pk = *(const uint4*)(h8b + (nbase + s) * HID + ch);
    *(uint4*)&R8[s * RSTR8 + ch] = pk;
  }
  __syncthreads();
  // edge-parallel C build (~8.5 iters/thread; batch/dinv L2-resident)
  const int e0 = bexcl2[j], e1 = bexcl2[j + 1];
  for (int e = e0 + tid; e < e1; e += 256) {
    int p = ebuf2[e];
    int s = (p >> 17) & 127;
    int d = p & 0x1FFFF;
    atomicAdd(&Cm[batch[d] * CP + s], dinv[d]);
  }
  for (int n = tid; n < validRows; n += 256) {
    long node = nbase + n;
    atomicAdd(&Cm[batch[node] * CP + n], dinv[node]);   // self term
  }
  __syncthreads();
  const int lane = tid & 63, wid = tid >> 6;
  const int m16 = lane & 15, quad = lane >> 4;
  f32x4 acc[4][2];
#pragma unroll
  for (int mt = 0; mt < 4; ++mt)
#pragma unroll
    for (int ntl = 0; ntl < 2; ++ntl) acc[mt][ntl] = (f32x4){0.f, 0.f, 0.f, 0.f};
#pragma unroll
  for (int kt = 0; kt < 4; ++kt) {
    union { uint_t p[4]; bf16x8 v; } bf[2];
#pragma unroll
    for (int ntl = 0; ntl < 2; ++ntl) {
      int nt = wid * 2 + ntl;
#pragma unroll
      for (int jj = 0; jj < 8; jj += 2) {
        uint_t byte0 = R8[(kt * 32 + quad * 8 + jj) * RSTR8 + nt * 16 + m16];
        uint_t byte1 = R8[(kt * 32 + quad * 8 + jj + 1) * RSTR8 + nt * 16 + m16];
        bf[ntl].p[jj >> 1] = fp8pair2bf(byte0, byte1);   // fp8 -> bf16 exact
      }
    }
#pragma unroll
    for (int mt = 0; mt < 4; ++mt) {
      float4 c0 = *(const float4*)&Cm[(mt * 16 + m16) * CP + kt * 32 + quad * 8];
      float4 c1 = *(const float4*)&Cm[(mt * 16 + m16) * CP + kt * 32 + quad * 8 + 4];
      union { uint_t p[4]; bf16x8 v; } af;
      af.p[0] = pkbf(c0.x, c0.y); af.p[1] = pkbf(c0.z, c0.w);
      af.p[2] = pkbf(c1.x, c1.y); af.p[3] = pkbf(c1.z, c1.w);
      acc[mt][0] = __builtin_amdgcn_mfma_f32_16x16x32_bf16(af.v, bf[0].v, acc[mt][0], 0, 0, 0);
      acc[mt][1] = __builtin_amdgcn_mfma_f32_16x16x32_bf16(af.v, bf[1].v, acc[mt][1], 0, 0, 0);
    }
  }
  // R26: fp32 atomic adds into the XCD-local slab (blockIdx&7 -> same-XCD
  // blocks share a 32KB L2-hot slab; each address gets one add per block,
  // different dwords of a line are independent at L2 -> no hot-spot).
  float* slab = slabs + (long)(j & 7) * (B * HID);
#pragma unroll
  for (int mt = 0; mt < 4; ++mt)
#pragma unroll
    for (int ntl = 0; ntl < 2; ++ntl)
#pragma unroll
      for (int r = 0; r < 4; ++r) {
        int g = mt * 16 + quad * 4 + r;
        int ch = (wid * 2 + ntl) * 16 + m16;
        atomicAdd(&slab[g * HID + ch], acc[mt][ntl][r]);
      }
}

// ---------------- final GEMM (slab-sum folded in; pool_reduce deleted) ----------------

__global__ __launch_bounds__(256) void k_final(const float* __restrict__ slabs,
                                               const int* __restrict__ starts,
                                               const float* __restrict__ W3,
                                               const float* __restrict__ b3,
                                               float* __restrict__ out) {
  __shared__ float p[HID];
  int g = blockIdx.x, tid = threadIdx.x;
  int len = starts[g + 1] - starts[g];
  float scale = 1.0f / fmaxf((float)len, 1.0f);
  if (tid < HID) {
    float a = 0.f;
#pragma unroll
    for (int k = 0; k < NSLAB; ++k) a += slabs[k * (B * HID) + g * HID + tid];
    p[tid] = a * scale;
  }
  __syncthreads();
  float a = b3[tid];
  for (int k = 0; k < HID; ++k) a = fmaf(p[k], W3[k * OUTD + tid], a);
  out[g * OUTD + tid] = a;
}

// ---------------- launch ----------------

extern "C" void kernel_launch(void* const* d_in, const int* in_sizes, int n_in,
                              void* d_out, int out_size, void* d_ws, size_t ws_size,
                              hipStream_t stream) {
  const float* x    = (const float*)d_in[0];
  const int*   eidx = (const int*)d_in[1];
  const int*   batch= (const int*)d_in[2];
  const float* W1   = (const float*)d_in[3];
  const float* b1   = (const float*)d_in[4];
  const float* W2   = (const float*)d_in[5];
  const float* b2   = (const float*)d_in[6];
  const float* W3   = (const float*)d_in[7];
  const float* b3   = (const float*)d_in[8];
  const float* resW = (const float*)d_in[9];
  const float* resb = (const float*)d_in[10];
  const float* g1   = (const float*)d_in[11];
  const float* bb1  = (const float*)d_in[12];
  const float* g2   = (const float*)d_in[13];
  const float* bb2  = (const float*)d_in[14];
  float* out = (float*)d_out;

  char* w = (char*)d_ws;
  size_t off = 0;
  auto alloc = [&](size_t bytes) {
    char* p = w + off;
    off = (off + bytes + 1023) & ~(size_t)1023;
    return p;
  };
  float* dinv   = (float*)alloc((size_t)N * 4);
  int*   rowptr = (int*)alloc((size_t)(N + 1) * 4);
  int*   colsrc = (int*)alloc((size_t)E * 4);
  int*   ebuf   = (int*)alloc((size_t)E * 4);
  int*   ebuf2  = (int*)alloc((size_t)E * 4);
  int*   hist   = (int*)alloc((size_t)GB * NBUK * 4);
  int*   hist2  = (int*)alloc((size_t)GB * NBUK * 4);
  int*   btotal = (int*)alloc((size_t)NBUK * 4);
  int*   btotal2= (int*)alloc((size_t)NBUK * 4);
  int*   bexcl  = (int*)alloc((size_t)(NBUK + 1) * 4);
  int*   bexcl2 = (int*)alloc((size_t)(NBUK + 1) * 4);
  int*   starts = (int*)alloc((size_t)(B + 1) * 4);
  float* slabs  = (float*)alloc((size_t)NSLAB * B * HID * 4);   // 256 KB
  ushort_t* xs16   = (ushort_t*)alloc((size_t)N * IND * 2);
  ushort_t* wpack  = (ushort_t*)alloc((size_t)HID * HID * 2);
  ushort_t* w1pack = (ushort_t*)alloc((size_t)8192 * 2);
  unsigned char* h8a = (unsigned char*)alloc((size_t)N * HID);
  unsigned char* h8b = (unsigned char*)alloc((size_t)N * HID);

  // ---- prep: hist + weight packs + seg starts + slab zero in ONE launch ----
  k_prep<<<GB + 96 + NSEG + 64, 256, 0, stream>>>(
      eidx, hist, hist2, W2, W1, resW, wpack, w1pack, batch, starts, slabs);
  k_bscan2x<<<2 * NBUK, 256, 0, stream>>>(hist, btotal, hist2, btotal2);
  k_bktscan2x<<<2, 256, 0, stream>>>(btotal, bexcl, btotal2, bexcl2, rowptr);
  k_scatter<<<GB, 1024, 0, stream>>>(eidx, hist, bexcl, hist2, bexcl2, ebuf, ebuf2);
  k_csr<<<NBUK, 256, 0, stream>>>(ebuf, bexcl, x, rowptr, dinv, colsrc, xs16);

  // ---- layer 1: fused gather + MFMA conv1 + LN1 + ReLU, fp8 out ----
  k_layer1<<<N / 16, 256, 0, stream>>>(xs16, x, rowptr, colsrc, w1pack,
                                       b1, resb, g1, bb1, dinv, h8a);

  // ---- layer 2: fp8 gather + MFMA GEMM + LN2 + ReLU, fp8 out ----
  k_layer2<<<N / 16, 256, 0, stream>>>(h8a, dinv, rowptr, colsrc,
                                       wpack, b2, g2, bb2, h8b);

  // ---- layer 3: per-bucket pool GEMM -> XCD-local fp32 atomic slabs ----
  k_pool3m<<<NBUK, 256, 0, stream>>>(h8b, bexcl2, ebuf2, batch, dinv, slabs);
  k_final<<<B, 256, 0, stream>>>(slabs, starts, W3, b3, out);
}

// Round 11
// 257.905 us; speedup vs baseline: 1.0455x; 1.0455x over previous
//
#include <hip/hip_runtime.h>
#include <hip/hip_bf16.h>
#include <hip/hip_fp16.h>
#include <hip/hip_fp8.h>

// GCN: N=100000 nodes, E=1600000 edges, B=64 graphs, 20 -> 128 -> 128 -> 256.
// Strategy log:
//  - gcn_conv(h,W) = (scatter_norm(h)) @ W; mean-pool commutes with W3.
//  - R1 sorted-batch seg starts; R3 two-level bucket-sort CSR.
//  - R4-R8: gathers pinned by random line traffic; fp8 payloads (R7).
//  - R9 lesson: edge-parallel scatter or bust. R11/14: GEMMs on MFMA.
//  - R12/13: layer-3 -> dense per-bucket GEMM + partial slabs + reduce.
//  - R15: layer2 gather: one row per 16-lane group -> 81 -> 48us (floor).
//  - R16: pool3m raw-fp8 staging; bf16 slabs; gather20b fused into conv1.
//  - R17/18: packed fp8 decode + v_cvt_pk_bf16_f32; k_prep merge. 304->295.
//  - R19 FAILED: NT stores broke CROSS-KERNEL L2 reuse.
//  - R20: k_scatter 256x1024: 295->292.6.
//  - R21: pool_reduce uint4+shfl: WIN (-16). Gather unroll 8: REGRESSION.
//    Lesson: random-gather kernels live on TLP, not ILP.
//  - R22: unrolls back to 4; 273.9. layer2 at random-line floor (47us).
//  - R23: SB=64: traffic fix must not sacrifice CU coverage (reverted).
//  - R24: 256 blk + XCD row perm l=(b&7)*32+(b>>3): 273.9->260.3.
//  - R25: scatter LDS staging sort: -1.6 (258.7). Gather floors PROVEN
//    compulsory (8 XCD x 11MB = 88MB L2-miss fill; any split >= 102MB).
//  - R26 FAILED (+10.9, reverted): pool slabs via global fp32 atomics.
//    pool3m 47.9us, WRITE 25MB (RMW), occ 21%, VALU 4% — atomic-issue-rate
//    bound. Lesson: coalesced store + vectorized reduce beats atomics when
//    each address takes ~100 contributions.
//  - R27 (this round): exact R25 revert (best verified 258.7us). All majors
//    now at proven floors: gathers compulsory-bound, scatter within ~2us of
//    best-of-two-attacks, pool3m at its 25.6MB round trip, reduce
//    vectorized. Expect ~258-260; next round likely ROOFLINE.

typedef unsigned short ushort_t;
typedef unsigned int uint_t;
typedef __attribute__((ext_vector_type(8))) short bf16x8;
typedef __attribute__((ext_vector_type(4))) float f32x4;
typedef __attribute__((ext_vector_type(2))) float f32x2;

constexpr int N  = 100000;
constexpr int E  = 1600000;
constexpr int B  = 64;
constexpr int IND = 20;
constexpr int HID = 128;
constexpr int OUTD = 256;

constexpr int NBUK = (N + 127) / 128;   // 782 buckets of 128 nodes
constexpr int GB   = 256;               // hist rows / scatter blocks
constexpr int EPB  = E / GB;            // 6250 edges per hist row
constexpr int BMAX = 3072;              // LDS cap per bucket (mean 2048, sd ~45)

// bf16 helpers (RNE pack, shift-unpack)
__device__ inline ushort_t f2bf(float f) {
  union { float f; uint_t u; } v; v.f = f;
  uint_t r = v.u + 0x7fffu + ((v.u >> 16) & 1u);
  return (ushort_t)(r >> 16);
}
__device__ inline float bflo(uint_t u) { return __uint_as_float(u << 16); }
__device__ inline float bfhi(uint_t u) { return __uint_as_float(u & 0xffff0000u); }

// packed f32x2 -> bf16x2 (RNE, identical to f2bf pair) in ONE VALU op
__device__ inline uint_t pkbf(float a, float b) {
  uint_t r;
  asm("v_cvt_pk_bf16_f32 %0, %1, %2" : "=v"(r) : "v"(a), "v"(b));
  return r;
}

// fp8 e4m3 helpers (HW cvt on gfx950; hip_fp8.h fallback)
#if defined(__has_builtin)
#if __has_builtin(__builtin_amdgcn_cvt_f32_fp8) && __has_builtin(__builtin_amdgcn_cvt_pk_fp8_f32)
#define FP8_HW 1
#endif
#if __has_builtin(__builtin_amdgcn_cvt_pk_f32_fp8)
#define FP8_PK 1
#endif
#endif

template <int S>
__device__ inline float fp8dec(uint_t u) {
#ifdef FP8_HW
  return __builtin_amdgcn_cvt_f32_fp8(u, S);
#else
  __hip_fp8_storage_t b = (__hip_fp8_storage_t)((u >> (8 * S)) & 0xffu);
  __half_raw hr = __hip_cvt_fp8_to_halfraw(b, __HIP_E4M3);
  return __half2float(*(__half*)&hr);
#endif
}

// packed decode: word W of u (bytes 2W,2W+1) -> float2 in one inst
template <int W>
__device__ inline f32x2 fp8dec2(uint_t u) {
#ifdef FP8_PK
  return __builtin_amdgcn_cvt_pk_f32_fp8(u, W != 0);
#else
  f32x2 r; r.x = fp8dec<W * 2>(u); r.y = fp8dec<W * 2 + 1>(u); return r;
#endif
}

template <bool W>
__device__ inline uint_t fp8pk2(float a, float b, uint_t old) {
#ifdef FP8_HW
  return __builtin_amdgcn_cvt_pk_fp8_f32(a, b, old, W);
#else
  uint_t lo = (uint_t)__hip_cvt_float_to_fp8(a, __HIP_SATFINITE, __HIP_E4M3);
  uint_t hi = (uint_t)__hip_cvt_float_to_fp8(b, __HIP_SATFINITE, __HIP_E4M3);
  uint_t pair = lo | (hi << 8);
  return W ? ((old & 0x0000ffffu) | (pair << 16)) : ((old & 0xffff0000u) | pair);
#endif
}

// two fp8 bytes (from different LDS rows) -> packed bf16 pair (b0 low)
__device__ inline uint_t fp8pair2bf(uint_t b0, uint_t b1) {
#ifdef FP8_PK
  f32x2 f = fp8dec2<0>(b0 | (b1 << 8));
  return pkbf(f.x, f.y);
#else
  return (uint_t)f2bf(fp8dec<0>(b0)) | ((uint_t)f2bf(fp8dec<0>(b1)) << 16);
#endif
}

// ---------------- merged prep: hist + weight packs + seg starts ----------------
// blocks [0,GB): edge histograms; [GB,GB+96): weight packs; rest: seg starts.

__global__ __launch_bounds__(256) void k_prep(const int* __restrict__ eidx,
                                              int* __restrict__ histd,
                                              int* __restrict__ hists,
                                              const float* __restrict__ W2,
                                              const float* __restrict__ W1,
                                              const float* __restrict__ resW,
                                              ushort_t* __restrict__ wpack,
                                              ushort_t* __restrict__ w1pack,
                                              const int* __restrict__ batch,
                                              int* __restrict__ starts) {
  const int bid = blockIdx.x;
  if (bid < GB) {
    __shared__ int hd[NBUK], hs[NBUK];
    for (int i = threadIdx.x; i < NBUK; i += 256) { hd[i] = 0; hs[i] = 0; }
    __syncthreads();
    const long base = (long)bid * EPB;
    for (int i = threadIdx.x; i < EPB; i += 256) {
      atomicAdd(&hs[eidx[base + i] >> 7], 1);
      atomicAdd(&hd[eidx[E + base + i] >> 7], 1);
    }
    __syncthreads();
    for (int i = threadIdx.x; i < NBUK; i += 256) {
      histd[(long)bid * NBUK + i] = hd[i];
      hists[(long)bid * NBUK + i] = hs[i];
    }
  } else if (bid < GB + 96) {
    // Pack W2 into MFMA B-frag order (16384) AND [W1|resW] K=64 pack (8192).
    int idx = (bid - GB) * 256 + threadIdx.x;
    if (idx < 16384) {
      int j = idx & 7, L = (idx >> 3) & 63, kt = (idx >> 9) & 3, t = idx >> 11;
      int k = kt * 32 + ((L >> 4) & 3) * 8 + j;
      int n = t * 16 + (L & 15);
      wpack[idx] = f2bf(W2[k * HID + n]);
    } else {
      int i2 = idx - 16384;
      int j = i2 & 7, L = (i2 >> 3) & 63, kt = (i2 >> 9) & 1, t = i2 >> 10;
      int k = kt * 32 + ((L >> 4) & 3) * 8 + j;
      int n = t * 16 + (L & 15);
      float v = 0.f;
      if (k < IND) v = W1[k * HID + n];
      else if (k >= 32 && k < 32 + IND) v = resW[(k - 32) * HID + n];
      w1pack[i2] = f2bf(v);
    }
  } else {
    int i = (bid - GB - 96) * 256 + threadIdx.x;
    if (i >= N) return;
    int b = batch[i];
    int prev = (i == 0) ? -1 : batch[i - 1];
    for (int g = prev + 1; g <= b; ++g) starts[g] = i;  // fires only at boundaries
    if (i == N - 1)
      for (int g = b + 1; g <= B; ++g) starts[g] = N;
  }
}

// ---------------- CSR builds: bucket sorts by dst AND by src ----------------

// Both per-bucket scans in one launch: grid = 2*NBUK.
__global__ __launch_bounds__(256) void k_bscan2x(int* __restrict__ histd,
                                                 int* __restrict__ btd,
                                                 int* __restrict__ hists,
                                                 int* __restrict__ bts) {
  __shared__ int s[256];
  const int which = (blockIdx.x >= NBUK);
  const int j = which ? blockIdx.x - NBUK : blockIdx.x;
  int* hist = which ? hists : histd;
  int* btotal = which ? bts : btd;
  const int tid = threadIdx.x;
  int v = hist[(long)tid * NBUK + j];
  s[tid] = v;
  for (int off = 1; off < 256; off <<= 1) {
    __syncthreads();
    int x = (tid >= off) ? s[tid - off] : 0;
    __syncthreads();
    s[tid] += x;
  }
  hist[(long)tid * NBUK + j] = s[tid] - v;   // exclusive within bucket
  if (tid == 255) btotal[j] = s[255];
}

// Both bucket-total scans in one launch: grid = 2.
__global__ __launch_bounds__(256) void k_bktscan2x(const int* __restrict__ btd,
                                                   int* __restrict__ bexcl,
                                                   const int* __restrict__ bts,
                                                   int* __restrict__ bexcl2,
                                                   int* __restrict__ rowptr) {
  __shared__ int s[256];
  const int* bt = blockIdx.x ? bts : btd;
  int* bx = blockIdx.x ? bexcl2 : bexcl;
  int tid = threadIdx.x;
  int base = tid * 4;
  int v0 = (base + 0 < NBUK) ? bt[base + 0] : 0;
  int v1 = (base + 1 < NBUK) ? bt[base + 1] : 0;
  int v2 = (base + 2 < NBUK) ? bt[base + 2] : 0;
  int v3 = (base + 3 < NBUK) ? bt[base + 3] : 0;
  int p0 = v0, p1 = p0 + v1, p2 = p1 + v2, p3 = p2 + v3;
  s[tid] = p3;
  for (int off = 1; off < 256; off <<= 1) {
    __syncthreads();
    int x = (tid >= off) ? s[tid - off] : 0;
    __syncthreads();
    s[tid] += x;
  }
  int excl = s[tid] - p3;
  if (base + 0 < NBUK) bx[base + 1] = excl + p0;
  if (base + 1 < NBUK) bx[base + 2] = excl + p1;
  if (base + 2 < NBUK) bx[base + 3] = excl + p2;
  if (base + 3 < NBUK) bx[base + 4] = excl + p3;
  if (tid == 0) { bx[0] = 0; if (blockIdx.x == 0) rowptr[N] = E; }
}

// Merged scatter with LDS staging sort (R25).
// ebuf (dst-order):  src(20b) | dstlow(7b)<<20
// ebuf2 (src-order): srclow(7b)<<17 | dst(17b)
// Per ordering: local count -> block scan -> bucket-ordered staged[] ->
// copy-out in staged order (coalesced write runs). R24 XCD row perm kept.
__global__ __launch_bounds__(1024) void k_scatter(const int* __restrict__ eidx,
                                                  const int* __restrict__ histd,
                                                  const int* __restrict__ bexcl,
                                                  const int* __restrict__ hists,
                                                  const int* __restrict__ bexcl2,
                                                  int* __restrict__ ebuf,
                                                  int* __restrict__ ebuf2) {
  __shared__ int lhist[NBUK];      // counts, then cursors
  __shared__ int lscan[NBUK];      // exclusive scan (staged base per bucket)
  __shared__ int gbase[NBUK];      // global base per bucket
  __shared__ int stmp[1024];       // scan temp
  __shared__ int staged[EPB];      // bucket-ordered payloads (25 KB)
  __shared__ ushort_t sbuk[EPB];   // bucket of each staged slot (12.5 KB)
  const int tid = threadIdx.x;
  const int l = ((blockIdx.x & 7) << 5) + (blockIdx.x >> 3);   // bijective 0..255
  const long hrow = (long)l * NBUK;
  const long base = (long)l * EPB;

#pragma unroll
  for (int pass = 0; pass < 2; ++pass) {
    const int* hist = pass ? hists : histd;
    const int* bx = pass ? bexcl2 : bexcl;
    int* out = pass ? ebuf2 : ebuf;
    // init: zero counts, load global bases
    for (int i = tid; i < NBUK; i += 1024) {
      lhist[i] = 0;
      gbase[i] = bx[i] + hist[hrow + i];
    }
    __syncthreads();
    // count
    for (int i = tid; i < EPB; i += 1024) {
      int key = eidx[(pass ? 0 : E) + base + i];   // dst for pass0, src for pass1
      atomicAdd(&lhist[key >> 7], 1);
    }
    __syncthreads();
    // block scan (Hillis-Steele over 1024, NBUK=782 zero-padded)
    {
      int v = (tid < NBUK) ? lhist[tid] : 0;
      stmp[tid] = v;
      for (int off = 1; off < 1024; off <<= 1) {
        __syncthreads();
        int x2 = (tid >= off) ? stmp[tid - off] : 0;
        __syncthreads();
        stmp[tid] += x2;
      }
      __syncthreads();
      if (tid < NBUK) {
        int ex = stmp[tid] - v;
        lscan[tid] = ex;
        lhist[tid] = ex;   // cursor
      }
    }
    __syncthreads();
    // scatter into staged (bucket-ordered)
    for (int i = tid; i < EPB; i += 1024) {
      int s = eidx[base + i];
      int d = eidx[E + base + i];
      int b = (pass ? s : d) >> 7;
      int pos = atomicAdd(&lhist[b], 1);
      staged[pos] = pass ? (((s & 127) << 17) | d) : (s | ((d & 127) << 20));
      sbuk[pos] = (ushort_t)b;
    }
    __syncthreads();
    // coalesced copy-out: staged order == global order within each bucket run
    for (int i = tid; i < EPB; i += 1024) {
      int b = sbuk[i];
      out[gbase[b] + (i - lscan[b])] = staged[i];
    }
    __syncthreads();
  }
}

// One block per dst-bucket: LDS counting sort -> rowptr/dinv/colsrc + xs16.
__global__ __launch_bounds__(256) void k_csr(const int* __restrict__ ebuf,
                                             const int* __restrict__ bexcl,
                                             const float* __restrict__ x,
                                             int* __restrict__ rowptr,
                                             float* __restrict__ dinv,
                                             int* __restrict__ colsrc,
                                             ushort_t* __restrict__ xs16) {
  __shared__ int deg[128], s[128], cur[128];
  __shared__ float dv[128];
  __shared__ int lout[BMAX];
  const int j = blockIdx.x, tid = threadIdx.x;
  const int e0 = bexcl[j], e1 = bexcl[j + 1];
  const int cnt = e1 - e0;
  if (tid < 128) deg[tid] = 0;
  __syncthreads();
  for (int i = tid; i < cnt; i += 256)
    atomicAdd(&deg[(ebuf[e0 + i] >> 20) & 127], 1);
  __syncthreads();
  int v = (tid < 128) ? deg[tid] : 0;
  if (tid < 128) s[tid] = v;
  for (int off = 1; off < 128; off <<= 1) {
    __syncthreads();
    int x2 = (tid < 128 && tid >= off) ? s[tid - off] : 0;
    __syncthreads();
    if (tid < 128) s[tid] += x2;
  }
  __syncthreads();
  if (tid < 128) {
    int ex = s[tid] - v;
    cur[tid] = ex;
    float d = rsqrtf((float)(1 + v));   // deg includes self-loop
    dv[tid] = d;
    int node = j * 128 + tid;
    if (node < N) {
      rowptr[node] = e0 + ex;
      dinv[node] = d;
    }
  }
  __syncthreads();
  if (cnt <= BMAX) {
    for (int i = tid; i < cnt; i += 256) {
      int p = ebuf[e0 + i];
      int pos = atomicAdd(&cur[(p >> 20) & 127], 1);
      lout[pos] = p & 0xFFFFF;
    }
    __syncthreads();
    for (int i = tid; i < cnt; i += 256) colsrc[e0 + i] = lout[i];
  } else {  // safety fallback
    for (int i = tid; i < cnt; i += 256) {
      int p = ebuf[e0 + i];
      int pos = atomicAdd(&cur[(p >> 20) & 127], 1);
      colsrc[e0 + pos] = p & 0xFFFFF;
    }
  }
  for (int idx = tid; idx < 128 * IND; idx += 256) {
    int n = idx / IND;
    long node = (long)j * 128 + n;
    if (node < N)
      xs16[node * IND + idx % IND] = f2bf(x[node * IND + idx % IND] * dv[n]);
  }
}

// ---------------- layer 1: fused 20-dim gather + MFMA conv1 + LN + ReLU ----------------

// A-tile: 16 nodes x K=64 (k<20: gathered aggx, 32<=k<52: bf16(x), else 0).
constexpr int ASTR = 72;    // bf16 A stride
constexpr int CSTR = 132;   // fp32 C stride

__global__ __launch_bounds__(256) void k_layer1(const ushort_t* __restrict__ xs16,
                                                const float* __restrict__ x,
                                                const int* __restrict__ rowptr,
                                                const int* __restrict__ colsrc,
                                                const ushort_t* __restrict__ w1pack,
                                                const float* __restrict__ b1,
                                                const float* __restrict__ resb,
                                                const float* __restrict__ g1,
                                                const float* __restrict__ bb1,
                                                const float* __restrict__ dinv,
                                                unsigned char* __restrict__ h8a) {
  __shared__ ushort_t A[16 * ASTR];   // 2.25 KB
  __shared__ float Cs[16 * CSTR];     // 8.25 KB
  const int tid = threadIdx.x;
  const long node0 = (long)blockIdx.x * 16;           // grid = N/16 exact
  // zero A, stage x into k in [32,52)
  for (int idx = tid; idx < 16 * ASTR; idx += 256) A[idx] = 0;
  __syncthreads();
  for (int idx = tid; idx < 16 * IND; idx += 256) {
    int n = idx / IND, k = idx % IND;
    A[n * ASTR + 32 + k] = f2bf(x[(node0 + n) * IND + k]);
  }
  // gather phase: 10 threads/node x 16 nodes = 160 active threads,
  // each owns 2 channels, serial over edges (unroll 4; 8 raised VGPR/cut occ).
  if (tid < 160) {
    int n = tid / 10, cc = (tid % 10) * 2;
    long i = node0 + n;
    float di = dinv[i];
    uint_t u = *(const uint_t*)(xs16 + i * IND + cc);
    float a0 = bflo(u), a1 = bfhi(u);
    int e0 = rowptr[i], e1 = rowptr[i + 1];
#pragma unroll 4
    for (int e = e0; e < e1; ++e) {
      int s = colsrc[e];
      uint_t v = *(const uint_t*)(xs16 + (long)s * IND + cc);
      a0 += bflo(v); a1 += bfhi(v);
    }
    *(uint_t*)&A[n * ASTR + cc] = pkbf(a0 * di, a1 * di);
  }
  __syncthreads();
  const int lane = tid & 63, w = tid >> 6;
  {
    const int arow = lane & 15, aq = lane >> 4;
    f32x4 acc0 = {0.f, 0.f, 0.f, 0.f}, acc1 = {0.f, 0.f, 0.f, 0.f};
    const int t0 = w * 2, t1 = t0 + 1;
#pragma unroll
    for (int kt = 0; kt < 2; ++kt) {
      bf16x8 af = *(const bf16x8*)&A[arow * ASTR + kt * 32 + aq * 8];
      bf16x8 b0 = *(const bf16x8*)&w1pack[(t0 * 2 + kt) * 512 + lane * 8];
      bf16x8 b1f = *(const bf16x8*)&w1pack[(t1 * 2 + kt) * 512 + lane * 8];
      acc0 = __builtin_amdgcn_mfma_f32_16x16x32_bf16(af, b0, acc0, 0, 0, 0);
      acc1 = __builtin_amdgcn_mfma_f32_16x16x32_bf16(af, b1f, acc1, 0, 0, 0);
    }
#pragma unroll
    for (int r = 0; r < 4; ++r) {
      Cs[(aq * 4 + r) * CSTR + t0 * 16 + arow] = acc0[r];
      Cs[(aq * 4 + r) * CSTR + t1 * 16 + arow] = acc1[r];
    }
  }
  __syncthreads();
  const int nidx = tid >> 5, col = (tid & 31) * 4;
  float4 bz = *(const float4*)&b1[col];
  float4 rz = *(const float4*)&resb[col];
  bz.x += rz.x; bz.y += rz.y; bz.z += rz.z; bz.w += rz.w;
  float4 gz = *(const float4*)&g1[col];
  float4 bbz = *(const float4*)&bb1[col];
#pragma unroll
  for (int m = 0; m < 2; ++m) {
    int nl = nidx + m * 8;
    long nm = node0 + nl;
    float4 o = *(const float4*)&Cs[nl * CSTR + col];
    o.x += bz.x; o.y += bz.y; o.z += bz.z; o.w += bz.w;
    float s = o.x + o.y + o.z + o.w;
    float q = o.x * o.x + o.y * o.y + o.z * o.z + o.w * o.w;
#pragma unroll
    for (int off = 1; off <= 16; off <<= 1) {
      s += __shfl_xor(s, off);
      q += __shfl_xor(q, off);
    }
    float mu = s * (1.f / 128.f);
    float var = q * (1.f / 128.f) - mu * mu;
    float rs = rsqrtf(var + 1e-5f);
    float y0 = fmaxf(fmaf((o.x - mu) * rs, gz.x, bbz.x), 0.f);
    float y1 = fmaxf(fmaf((o.y - mu) * rs, gz.y, bbz.y), 0.f);
    float y2 = fmaxf(fmaf((o.z - mu) * rs, gz.z, bbz.z), 0.f);
    float y3 = fmaxf(fmaf((o.w - mu) * rs, gz.w, bbz.w), 0.f);
    float di = dinv[nm];
    uint_t p = fp8pk2<false>(y0 * di, y1 * di, 0u);
    p = fp8pk2<true>(y2 * di, y3 * di, p);
    *(uint_t*)&h8a[nm * HID + col] = p;
  }
}

// ---------------- layer 2: fp8 gather + MFMA GEMM + LN + ReLU ----------------

constexpr int XSTR = 136;   // bf16 stride

__global__ __launch_bounds__(256) void k_layer2(const unsigned char* __restrict__ h8a,
                                                const float* __restrict__ dinv,
                                                const int* __restrict__ rowptr,
                                                const int* __restrict__ colsrc,
                                                const ushort_t* __restrict__ wpack,
                                                const float* __restrict__ bias,
                                                const float* __restrict__ g2,
                                                const float* __restrict__ bb2,
                                                unsigned char* __restrict__ h8b) {
  __shared__ ushort_t XsB[16 * XSTR];   // 4.25 KB bf16 gathered X
  __shared__ float Cs[16 * CSTR];       // 8.25 KB fp32 GEMM out
  const int tid = threadIdx.x;
  const long node0 = (long)blockIdx.x * 16;           // grid = N/16 exact
  const int lane = tid & 63, w = tid >> 6;
  // ---- phase 1: one ROW per 16-lane group; rows parallel; no reduce ----
  // packed decode: 4x v_cvt_pk_f32_fp8 + 4x f32x2 add per edge
  // (unroll 4: TLP > ILP for random gathers; unroll 8 cost 10% occupancy)
  {
    const int grp = lane >> 4, l16 = lane & 15, c8 = l16 * 8;
    const long i = node0 + w * 4 + grp;
    const float di = dinv[i];
    f32x2 a0, a1, a2, a3;
    {   // self term (row already carries dinv[i])
      uint2 u = *(const uint2*)(h8a + i * HID + c8);
      a0 = fp8dec2<0>(u.x); a1 = fp8dec2<1>(u.x);
      a2 = fp8dec2<0>(u.y); a3 = fp8dec2<1>(u.y);
    }
    const int e0 = rowptr[i], e1 = rowptr[i + 1];
#pragma unroll 4
    for (int e = e0; e < e1; ++e) {
      int s = colsrc[e];
      uint2 u = *(const uint2*)(h8a + (long)s * HID + c8);
      a0 += fp8dec2<0>(u.x); a1 += fp8dec2<1>(u.x);
      a2 += fp8dec2<0>(u.y); a3 += fp8dec2<1>(u.y);
    }
    uint_t p0 = pkbf(a0.x * di, a0.y * di);
    uint_t p1 = pkbf(a1.x * di, a1.y * di);
    uint_t p2 = pkbf(a2.x * di, a2.y * di);
    uint_t p3 = pkbf(a3.x * di, a3.y * di);
    *(uint4*)&XsB[(w * 4 + grp) * XSTR + c8] = make_uint4(p0, p1, p2, p3);
  }
  __syncthreads();
  // ---- phase 2: MFMA. Wave w covers n-tiles {2w, 2w+1}. ----
  {
    const int arow = lane & 15, aq = lane >> 4;
    f32x4 acc0 = {0.f, 0.f, 0.f, 0.f}, acc1 = {0.f, 0.f, 0.f, 0.f};
    const int t0 = w * 2, t1 = w * 2 + 1;
#pragma unroll
    for (int kt = 0; kt < 4; ++kt) {
      bf16x8 af = *(const bf16x8*)&XsB[arow * XSTR + kt * 32 + aq * 8];
      bf16x8 b0 = *(const bf16x8*)&wpack[(t0 * 4 + kt) * 512 + lane * 8];
      bf16x8 b1 = *(const bf16x8*)&wpack[(t1 * 4 + kt) * 512 + lane * 8];
      acc0 = __builtin_amdgcn_mfma_f32_16x16x32_bf16(af, b0, acc0, 0, 0, 0);
      acc1 = __builtin_amdgcn_mfma_f32_16x16x32_bf16(af, b1, acc1, 0, 0, 0);
    }
#pragma unroll
    for (int r = 0; r < 4; ++r) {
      Cs[(aq * 4 + r) * CSTR + t0 * 16 + arow] = acc0[r];
      Cs[(aq * 4 + r) * CSTR + t1 * 16 + arow] = acc1[r];
    }
  }
  __syncthreads();
  // ---- phase 3: bias + residual(fp8 h8a) + LN + ReLU + fp8 store ----
  const int nidx = tid >> 5;
  const int col = (tid & 31) * 4;
  float4 bz = *(const float4*)&bias[col];
  float4 gz = *(const float4*)&g2[col];
  float4 bbz = *(const float4*)&bb2[col];
#pragma unroll
  for (int m = 0; m < 2; ++m) {
    int nl = nidx + m * 8;
    long nm = node0 + nl;
    float di = dinv[nm];
    float rdi = 1.0f / di;
    uint_t ur = *(const uint_t*)&h8a[nm * HID + col];   // fp8 residual (L2-hot)
    f32x2 r01 = fp8dec2<0>(ur), r23 = fp8dec2<1>(ur);
    float4 o = *(const float4*)&Cs[nl * CSTR + col];
    o.x += bz.x + r01.x * rdi;
    o.y += bz.y + r01.y * rdi;
    o.z += bz.z + r23.x * rdi;
    o.w += bz.w + r23.y * rdi;
    float s = o.x + o.y + o.z + o.w;
    float q = o.x * o.x + o.y * o.y + o.z * o.z + o.w * o.w;
#pragma unroll
    for (int off = 1; off <= 16; off <<= 1) {
      s += __shfl_xor(s, off);
      q += __shfl_xor(q, off);
    }
    float mu = s * (1.f / 128.f);
    float var = q * (1.f / 128.f) - mu * mu;
    float rs = rsqrtf(var + 1e-5f);
    float y0 = fmaxf(fmaf((o.x - mu) * rs, gz.x, bbz.x), 0.f);
    float y1 = fmaxf(fmaf((o.y - mu) * rs, gz.y, bbz.y), 0.f);
    float y2 = fmaxf(fmaf((o.z - mu) * rs, gz.z, bbz.z), 0.f);
    float y3 = fmaxf(fmaf((o.w - mu) * rs, gz.w, bbz.w), 0.f);
    uint_t p = fp8pk2<false>(y0 * di, y1 * di, 0u);
    p = fp8pk2<true>(y2 * di, y3 * di, p);
    *(uint_t*)&h8b[nm * HID + col] = p;
  }
}

// ---------------- layer 3: per-bucket dense pool GEMM ----------------

constexpr int RSTR8 = 136;  // fp8 row stride (bytes, 8B aligned)
constexpr int CP    = 132;  // fp32 row stride for C

__global__ __launch_bounds__(256) void k_pool3m(const unsigned char* __restrict__ h8b,
                                                const int* __restrict__ bexcl2,
                                                const int* __restrict__ ebuf2,
                                                const int* __restrict__ batch,
                                                const float* __restrict__ dinv,
                                                ushort_t* __restrict__ partial) {
  __shared__ float Cm[B * CP];            // 33.8 KB
  __shared__ unsigned char R8[128 * RSTR8];  // 17.4 KB raw fp8 rows
  const int j = blockIdx.x, tid = threadIdx.x;
  const long nbase = (long)j * 128;
  const int validRows = min(128, N - (int)nbase);
  for (int i = tid; i < B * CP; i += 256) Cm[i] = 0.f;
  for (int i = tid; i < 128 * (HID / 16); i += 256) {   // 16B per thread
    int s = i >> 3;
    int ch = (i & 7) * 16;
    uint4 pk = make_uint4(0u, 0u, 0u, 0u);
    if (s < validRows)
      pk = *(const uint4*)(h8b + (nbase + s) * HID + ch);
    *(uint4*)&R8[s * RSTR8 + ch] = pk;
  }
  __syncthreads();
  // edge-parallel C build (~8.5 iters/thread; batch/dinv L2-resident)
  const int e0 = bexcl2[j], e1 = bexcl2[j + 1];
  for (int e = e0 + tid; e < e1; e += 256) {
    int p = ebuf2[e];
    int s = (p >> 17) & 127;
    int d = p & 0x1FFFF;
    atomicAdd(&Cm[batch[d] * CP + s], dinv[d]);
  }
  for (int n = tid; n < validRows; n += 256) {
    long node = nbase + n;
    atomicAdd(&Cm[batch[node] * CP + n], dinv[node]);   // self term
  }
  __syncthreads();
  const int lane = tid & 63, wid = tid >> 6;
  const int m16 = lane & 15, quad = lane >> 4;
  f32x4 acc[4][2];
#pragma unroll
  for (int mt = 0; mt < 4; ++mt)
#pragma unroll
    for (int ntl = 0; ntl < 2; ++ntl) acc[mt][ntl] = (f32x4){0.f, 0.f, 0.f, 0.f};
#pragma unroll
  for (int kt = 0; kt < 4; ++kt) {
    union { uint_t p[4]; bf16x8 v; } bf[2];
#pragma unroll
    for (int ntl = 0; ntl < 2; ++ntl) {
      int nt = wid * 2 + ntl;
#pragma unroll
      for (int jj = 0; jj < 8; jj += 2) {
        uint_t byte0 = R8[(kt * 32 + quad * 8 + jj) * RSTR8 + nt * 16 + m16];
        uint_t byte1 = R8[(kt * 32 + quad * 8 + jj + 1) * RSTR8 + nt * 16 + m16];
        bf[ntl].p[jj >> 1] = fp8pair2bf(byte0, byte1);   // fp8 -> bf16 exact
      }
    }
#pragma unroll
    for (int mt = 0; mt < 4; ++mt) {
      float4 c0 = *(const float4*)&Cm[(mt * 16 + m16) * CP + kt * 32 + quad * 8];
      float4 c1 = *(const float4*)&Cm[(mt * 16 + m16) * CP + kt * 32 + quad * 8 + 4];
      union { uint_t p[4]; bf16x8 v; } af;
      af.p[0] = pkbf(c0.x, c0.y); af.p[1] = pkbf(c0.z, c0.w);
      af.p[2] = pkbf(c1.x, c1.y); af.p[3] = pkbf(c1.z, c1.w);
      acc[mt][0] = __builtin_amdgcn_mfma_f32_16x16x32_bf16(af.v, bf[0].v, acc[mt][0], 0, 0, 0);
      acc[mt][1] = __builtin_amdgcn_mfma_f32_16x16x32_bf16(af.v, bf[1].v, acc[mt][1], 0, 0, 0);
    }
  }
  // bf16 partial slab (plain coalesced stores)
  ushort_t* slab = partial + (long)j * (B * HID);
#pragma unroll
  for (int mt = 0; mt < 4; ++mt)
#pragma unroll
    for (int ntl = 0; ntl < 2; ++ntl)
#pragma unroll
      for (int r = 0; r < 4; ++r) {
        int g = mt * 16 + quad * 4 + r;
        int ch = (wid * 2 + ntl) * 16 + m16;
        slab[g * HID + ch] = f2bf(acc[mt][ntl][r]);
      }
}

// R21: vectorized reduce. 128 blocks; block covers 64 outputs.
// thread: ol = tid&7 (8 thr x 8 ch = 64 outputs), jl = tid>>3 (32-way j).
// uint4 (16B) loads replace the old scalar 2B loads (G13).
__global__ __launch_bounds__(256) void k_pool_reduce(const ushort_t* __restrict__ partial,
                                                     float* __restrict__ pooled) {
  __shared__ float s[4][64];
  const int tid = threadIdx.x;
  const int ol = tid & 7, jl = tid >> 3;
  const int o0 = blockIdx.x * 64 + ol * 8;
  float a0 = 0.f, a1 = 0.f, a2 = 0.f, a3 = 0.f,
        a4 = 0.f, a5 = 0.f, a6 = 0.f, a7 = 0.f;
#pragma unroll 2
  for (int j = jl; j < NBUK; j += 32) {
    uint4 v = *(const uint4*)&partial[(long)j * (B * HID) + o0];
    a0 += bflo(v.x); a1 += bfhi(v.x);
    a2 += bflo(v.y); a3 += bfhi(v.y);
    a4 += bflo(v.z); a5 += bfhi(v.z);
    a6 += bflo(v.w); a7 += bfhi(v.w);
  }
  // reduce the 8 jl-slices within each wave (lane bits 3..5)
#pragma unroll
  for (int off = 8; off <= 32; off <<= 1) {
    a0 += __shfl_xor(a0, off); a1 += __shfl_xor(a1, off);
    a2 += __shfl_xor(a2, off); a3 += __shfl_xor(a3, off);
    a4 += __shfl_xor(a4, off); a5 += __shfl_xor(a5, off);
    a6 += __shfl_xor(a6, off); a7 += __shfl_xor(a7, off);
  }
  const int w = tid >> 6, lane = tid & 63;
  if (lane < 8) {
    float* d = &s[w][lane * 8];
    d[0] = a0; d[1] = a1; d[2] = a2; d[3] = a3;
    d[4] = a4; d[5] = a5; d[6] = a6; d[7] = a7;
  }
  __syncthreads();
  if (tid < 64)
    pooled[blockIdx.x * 64 + tid] = s[0][tid] + s[1][tid] + s[2][tid] + s[3][tid];
}

// ---------------- final GEMM ----------------

__global__ __launch_bounds__(256) void k_final(const float* __restrict__ pooled,
                                               const int* __restrict__ starts,
                                               const float* __restrict__ W3,
                                               const float* __restrict__ b3,
                                               float* __restrict__ out) {
  __shared__ float p[HID];
  int g = blockIdx.x, tid = threadIdx.x;
  int len = starts[g + 1] - starts[g];
  float scale = 1.0f / fmaxf((float)len, 1.0f);
  if (tid < HID) p[tid] = pooled[g * HID + tid] * scale;
  __syncthreads();
  float a = b3[tid];
  for (int k = 0; k < HID; ++k) a = fmaf(p[k], W3[k * OUTD + tid], a);
  out[g * OUTD + tid] = a;
}

// ---------------- launch ----------------

extern "C" void kernel_launch(void* const* d_in, const int* in_sizes, int n_in,
                              void* d_out, int out_size, void* d_ws, size_t ws_size,
                              hipStream_t stream) {
  const float* x    = (const float*)d_in[0];
  const int*   eidx = (const int*)d_in[1];
  const int*   batch= (const int*)d_in[2];
  const float* W1   = (const float*)d_in[3];
  const float* b1   = (const float*)d_in[4];
  const float* W2   = (const float*)d_in[5];
  const float* b2   = (const float*)d_in[6];
  const float* W3   = (const float*)d_in[7];
  const float* b3   = (const float*)d_in[8];
  const float* resW = (const float*)d_in[9];
  const float* resb = (const float*)d_in[10];
  const float* g1   = (const float*)d_in[11];
  const float* bb1  = (const float*)d_in[12];
  const float* g2   = (const float*)d_in[13];
  const float* bb2  = (const float*)d_in[14];
  float* out = (float*)d_out;

  char* w = (char*)d_ws;
  size_t off = 0;
  auto alloc = [&](size_t bytes) {
    char* p = w + off;
    off = (off + bytes + 1023) & ~(size_t)1023;
    return p;
  };
  float* dinv   = (float*)alloc((size_t)N * 4);
  int*   rowptr = (int*)alloc((size_t)(N + 1) * 4);
  int*   colsrc = (int*)alloc((size_t)E * 4);
  int*   ebuf   = (int*)alloc((size_t)E * 4);
  int*   ebuf2  = (int*)alloc((size_t)E * 4);
  int*   hist   = (int*)alloc((size_t)GB * NBUK * 4);
  int*   hist2  = (int*)alloc((size_t)GB * NBUK * 4);
  int*   btotal = (int*)alloc((size_t)NBUK * 4);
  int*   btotal2= (int*)alloc((size_t)NBUK * 4);
  int*   bexcl  = (int*)alloc((size_t)(NBUK + 1) * 4);
  int*   bexcl2 = (int*)alloc((size_t)(NBUK + 1) * 4);
  int*   starts = (int*)alloc((size_t)(B + 1) * 4);
  float* pooled = (float*)alloc((size_t)B * HID * 4);
  ushort_t* xs16   = (ushort_t*)alloc((size_t)N * IND * 2);
  ushort_t* wpack  = (ushort_t*)alloc((size_t)HID * HID * 2);
  ushort_t* w1pack = (ushort_t*)alloc((size_t)8192 * 2);
  unsigned char* h8a = (unsigned char*)alloc((size_t)N * HID);
  unsigned char* h8b = (unsigned char*)alloc((size_t)N * HID);
  ushort_t* partial = (ushort_t*)alloc((size_t)NBUK * B * HID * 2);  // 12.8 MB

  // ---- prep: hist + weight packs + seg starts in ONE launch ----
  k_prep<<<GB + 96 + (N + 255) / 256, 256, 0, stream>>>(
      eidx, hist, hist2, W2, W1, resW, wpack, w1pack, batch, starts);
  k_bscan2x<<<2 * NBUK, 256, 0, stream>>>(hist, btotal, hist2, btotal2);
  k_bktscan2x<<<2, 256, 0, stream>>>(btotal, bexcl, btotal2, bexcl2, rowptr);
  k_scatter<<<GB, 1024, 0, stream>>>(eidx, hist, bexcl, hist2, bexcl2, ebuf, ebuf2);
  k_csr<<<NBUK, 256, 0, stream>>>(ebuf, bexcl, x, rowptr, dinv, colsrc, xs16);

  // ---- layer 1: fused gather + MFMA conv1 + LN1 + ReLU, fp8 out ----
  k_layer1<<<N / 16, 256, 0, stream>>>(xs16, x, rowptr, colsrc, w1pack,
                                       b1, resb, g1, bb1, dinv, h8a);

  // ---- layer 2: fp8 gather + MFMA GEMM + LN2 + ReLU, fp8 out ----
  k_layer2<<<N / 16, 256, 0, stream>>>(h8a, dinv, rowptr, colsrc,
                                       wpack, b2, g2, bb2, h8b);

  // ---- layer 3: dense per-bucket pool GEMM -> bf16 slabs -> reduce ----
  k_pool3m<<<NBUK, 256, 0, stream>>>(h8b, bexcl2, ebuf2, batch, dinv, partial);
  k_pool_reduce<<<(B * HID) / 64, 256, 0, stream>>>(partial, pooled);
  k_final<<<B, 256, 0, stream>>>(pooled, starts, W3, b3, out);
}